// Round 9
// baseline (197.768 us; speedup 1.0000x reference)
//
#include <hip/hip_runtime.h>
#include <math.h>

#define WAY   32
#define QUERY 128
#define FEAT  640
#define NPAIR 992
#define WQ    4096
#define NB    256     // blocks in the fused kernel: 1 per CU, all co-resident

typedef short bf16x8  __attribute__((ext_vector_type(8)));
typedef short short4v __attribute__((ext_vector_type(4)));
typedef float f32x4   __attribute__((ext_vector_type(4)));

static __device__ __forceinline__ float leaky(float v) {
    return v >= 0.0f ? v : 0.2f * v;
}
static __device__ __forceinline__ float dot4(float4 a, float4 b) {
    return a.x * b.x + a.y * b.y + a.z * b.z + a.w * b.w;
}
static __device__ __forceinline__ unsigned bf16_rne(float x) {
    unsigned u = __builtin_bit_cast(unsigned, x);
    return (u + 0x7FFFu + ((u >> 16) & 1u)) >> 16;
}
static __device__ __forceinline__ void split2(float x, short& hi, short& lo) {
    unsigned h = bf16_rne(x);
    float fh = __builtin_bit_cast(float, h << 16);
    hi = (short)h;
    lo = (short)bf16_rne(x - fh);
}

// Device-scope grid barrier (generation protocol). All NB blocks co-resident.
// cnt must be 0 at kernel entry (k_zero ensures); gen any consistent value.
static __device__ __forceinline__ void gsync(int* cnt, int* gen) {
    __syncthreads();
    if (threadIdx.x == 0) {
        __threadfence();   // flush this XCD's writes to device scope
        int g = __hip_atomic_load(gen, __ATOMIC_RELAXED, __HIP_MEMORY_SCOPE_AGENT);
        int arrived = __hip_atomic_fetch_add(cnt, 1, __ATOMIC_ACQ_REL, __HIP_MEMORY_SCOPE_AGENT);
        if (arrived == NB - 1) {
            __hip_atomic_store(cnt, 0, __ATOMIC_RELAXED, __HIP_MEMORY_SCOPE_AGENT);
            __hip_atomic_store(gen, g + 1, __ATOMIC_RELEASE, __HIP_MEMORY_SCOPE_AGENT);
        } else {
            while (__hip_atomic_load(gen, __ATOMIC_ACQUIRE, __HIP_MEMORY_SCOPE_AGENT) == g)
                __builtin_amdgcn_s_sleep(8);
        }
        __threadfence();   // invalidate stale lines before post-barrier reads
    }
    __syncthreads();
}

__global__ void k_zero(int* sync) {
    if (threadIdx.x < 2) sync[threadIdx.x] = 0;
}

// ---------------------------------------------------------------------------
// Fused persistent kernel: 256 blocks x 256 threads.
//  Phase A (720 vb): A'[i,o]=S[i].W1[o,:640]+b1[o]; B'[i,o]=S[i].W1[o,640:];
//                    + split W2 -> whi/wlo bf16
//  Phase B (310 vb): bf16x3 MFMA GEMM h2=leaky(h1@W2^T+b2), column-summed
//                    in-register into part[pt][2][640] (h2 never stored)
//  Phase C (80 vb):  m=(colsum/31)^4; V=-2mS, M=m, G=mS^2 as bf16 hi/lo
//  Phase D (256 vb): out[q,wi] = -sqrt(q.V + q^2.M + 1.G) via 14 mfma chains
// ---------------------------------------------------------------------------
__global__ __launch_bounds__(256) void k_all(const float* __restrict__ S,
                                             const float* __restrict__ Q,
                                             const float* __restrict__ W1,
                                             const float* __restrict__ b1,
                                             const float* __restrict__ W2,
                                             const float* __restrict__ b2,
                                             float* __restrict__ A,
                                             float* __restrict__ B,
                                             unsigned short* __restrict__ whi,
                                             unsigned short* __restrict__ wlo,
                                             float* __restrict__ part,
                                             unsigned short* __restrict__ Vhi,
                                             unsigned short* __restrict__ Vlo,
                                             unsigned short* __restrict__ Mhi,
                                             unsigned short* __restrict__ Mlo,
                                             unsigned short* __restrict__ Ghi,
                                             unsigned short* __restrict__ Glo,
                                             int* __restrict__ sync,
                                             float* __restrict__ out) {
    __shared__ __align__(16) char smem[24576];
    const int bx  = blockIdx.x;
    const int tid = threadIdx.x;
    const int lane = tid & 63;
    const int w    = tid >> 6;
    const int l15 = lane & 15, l4 = lane >> 4;

    // ================= Phase A =================
    {
        struct PreS { float4 shS[32][33]; float red1[128]; };
        PreS& sm = *reinterpret_cast<PreS*>(smem);
        for (int vb = bx; vb < 720; vb += NB) {
            if (vb < 320) {
                const int half = vb / 160;
                const int o0   = (vb % 160) * 4;
                const int i  = tid & 31;
                const int ol = (tid >> 5) & 3;
                const int fh = tid >> 7;
                const float4* Wrow = (const float4*)(W1 + (o0 + ol) * (2 * FEAT) + half * FEAT);
                float acc = 0.0f;
                for (int f0 = 0; f0 < FEAT; f0 += 128) {
                    __syncthreads();
#pragma unroll
                    for (int s = 0; s < 4; ++s) {
                        int flat = tid + 256 * s;
                        int si = flat >> 5, sf = flat & 31;
                        sm.shS[si][sf] = *(const float4*)(S + si * FEAT + f0 + 4 * sf);
                    }
                    __syncthreads();
                    const int kb = (f0 >> 2) + fh * 16;
#pragma unroll
                    for (int k = 0; k < 16; ++k)
                        acc += dot4(sm.shS[i][fh * 16 + k], Wrow[kb + k]);
                }
                if (fh) sm.red1[tid & 127] = acc;
                __syncthreads();
                if (!fh) {
                    float tot = acc + sm.red1[tid & 127];
                    if (half == 0) A[i * FEAT + o0 + ol] = tot + b1[o0 + ol];
                    else           B[i * FEAT + o0 + ol] = tot;
                }
                __syncthreads();
            } else {
                int e = (vb - 320) * 1024 + tid * 4;
                float4 wv = *(const float4*)(W2 + e);
                short h0, l0, h1, l1, h2, l2, h3, l3;
                split2(wv.x, h0, l0); split2(wv.y, h1, l1);
                split2(wv.z, h2, l2); split2(wv.w, h3, l3);
                *(short4v*)(whi + e) = (short4v){h0, h1, h2, h3};
                *(short4v*)(wlo + e) = (short4v){l0, l1, l2, l3};
            }
        }
    }
    gsync(sync, sync + 1);

    // ================= Phase B =================
    {
        struct K3S {
            short lsA[2][2][4][32][8];   // [buf][hi/lo][kc][prow][8]
            short lsB[2][2][4][64][8];   // [buf][hi/lo][kc][orow][8]
        };
        K3S& sm = *reinterpret_cast<K3S*>(smem);
        for (int vb = bx; vb < 310; vb += NB) {
            const int pt = vb % 31;
            const int p0 = pt * 32;
            const int o0 = (vb / 31) * 64;

            const int ar  = tid >> 3;
            const int ac4 = (tid & 7) << 2;
            const int akc = ac4 >> 3;
            const int aof = ac4 & 7;
            const int p = p0 + ar;
            const int ia = p / 31;
            const int jj = p % 31;
            const int ja = jj + (jj >= ia ? 1 : 0);
            const float* Arow = A + ia * FEAT;
            const float* Brow = B + ja * FEAT;
            const int br = tid >> 2;
            const int bk = tid & 3;
            const unsigned short* Whr = whi + (size_t)(o0 + br) * FEAT;
            const unsigned short* Wlr = wlo + (size_t)(o0 + br) * FEAT;

            float4 ra, rb;
            bf16x8 rwh, rwl;
            ra  = *(const float4*)(Arow + ac4);
            rb  = *(const float4*)(Brow + ac4);
            rwh = *(const bf16x8*)(Whr + bk * 8);
            rwl = *(const bf16x8*)(Wlr + bk * 8);

            f32x4 acc[2] = {};

            for (int t = 0; t < FEAT / 32; ++t) {
                const int buf = t & 1;
                {
                    float h[4];
                    h[0] = leaky(ra.x + rb.x);
                    h[1] = leaky(ra.y + rb.y);
                    h[2] = leaky(ra.z + rb.z);
                    h[3] = leaky(ra.w + rb.w);
                    short hi[4], lo[4];
#pragma unroll
                    for (int j = 0; j < 4; ++j) split2(h[j], hi[j], lo[j]);
                    *(short4v*)&sm.lsA[buf][0][akc][ar][aof] = (short4v){hi[0], hi[1], hi[2], hi[3]};
                    *(short4v*)&sm.lsA[buf][1][akc][ar][aof] = (short4v){lo[0], lo[1], lo[2], lo[3]};
                    *(bf16x8*)&sm.lsB[buf][0][bk][br][0] = rwh;
                    *(bf16x8*)&sm.lsB[buf][1][bk][br][0] = rwl;
                }
                __syncthreads();
                if (t < FEAT / 32 - 1) {
                    const int f0 = (t + 1) * 32;
                    ra  = *(const float4*)(Arow + f0 + ac4);
                    rb  = *(const float4*)(Brow + f0 + ac4);
                    rwh = *(const bf16x8*)(Whr + f0 + bk * 8);
                    rwl = *(const bf16x8*)(Wlr + f0 + bk * 8);
                }
                bf16x8 ah[2], al[2], bh, bl;
#pragma unroll
                for (int rt = 0; rt < 2; ++rt) {
                    ah[rt] = *(const bf16x8*)&sm.lsA[buf][0][l4][rt * 16 + l15][0];
                    al[rt] = *(const bf16x8*)&sm.lsA[buf][1][l4][rt * 16 + l15][0];
                }
                bh = *(const bf16x8*)&sm.lsB[buf][0][l4][w * 16 + l15][0];
                bl = *(const bf16x8*)&sm.lsB[buf][1][l4][w * 16 + l15][0];
#pragma unroll
                for (int rt = 0; rt < 2; ++rt) {
                    acc[rt] = __builtin_amdgcn_mfma_f32_16x16x32_bf16(ah[rt], bh, acc[rt], 0, 0, 0);
                    acc[rt] = __builtin_amdgcn_mfma_f32_16x16x32_bf16(ah[rt], bl, acc[rt], 0, 0, 0);
                    acc[rt] = __builtin_amdgcn_mfma_f32_16x16x32_bf16(al[rt], bh, acc[rt], 0, 0, 0);
                }
            }

            // colsum epilogue
            const int oo = o0 + w * 16 + l15;
            const float b2v = b2[oo];
            const int wi0 = p0 / 31;
            const int rsplit = (wi0 + 1) * 31 - p0;
            float s0 = 0.0f, s1 = 0.0f;
#pragma unroll
            for (int r = 0; r < 4; ++r) {
                float v = leaky(acc[0][r] + b2v);
                if (l4 * 4 + r < rsplit) s0 += v; else s1 += v;
                v = leaky(acc[1][r] + b2v);
                if (16 + l4 * 4 + r < rsplit) s0 += v; else s1 += v;
            }
            s0 += __shfl_xor(s0, 16, 64);
            s0 += __shfl_xor(s0, 32, 64);
            s1 += __shfl_xor(s1, 16, 64);
            s1 += __shfl_xor(s1, 32, 64);
            if (l4 == 0) {
                part[(pt * 2 + 0) * FEAT + oo] = s0;
                part[(pt * 2 + 1) * FEAT + oo] = s1;
            }
            __syncthreads();
        }
    }
    gsync(sync, sync + 1);

    // ================= Phase C =================
    if (bx < 80) {
        const int e  = bx * 256 + tid;
        const int wi = e / FEAT;
        const int o  = e % FEAT;
        const int pa = (31 * wi) >> 5;
        const int pb = (31 * wi + 30) >> 5;
        const int ha = wi - (32 * pa) / 31;
        const int hb = wi - (32 * pb) / 31;
        float cs = part[(pa * 2 + ha) * FEAT + o];
        if (pa != pb) cs += part[(pb * 2 + hb) * FEAT + o];
        float c1 = cs * (1.0f / 31.0f);
        float c2 = c1 * c1;
        float m  = c2 * c2;
        float sv = S[wi * FEAT + o];
        short h, l;
        split2(-2.0f * m * sv, h, l);
        Vhi[e] = (unsigned short)h;  Vlo[e] = (unsigned short)l;
        split2(m, h, l);
        Mhi[e] = (unsigned short)h;  Mlo[e] = (unsigned short)l;
        split2(m * sv * sv, h, l);
        Ghi[e] = (unsigned short)h;  Glo[e] = (unsigned short)l;
    }
    gsync(sync, sync + 1);

    // ================= Phase D =================
    {
        float (&red)[4][16][32] = *reinterpret_cast<float (*)[4][16][32]>(smem);
        const int q0 = bx * 16;
        const float* Qrow = Q + (size_t)(q0 + l15) * FEAT + l4 * 8;

        bf16x8 ones;
#pragma unroll
        for (int j = 0; j < 8; ++j) ones[j] = (short)0x3F80;

        f32x4 c[2][7] = {};

        for (int s = 0; s < 5; ++s) {
            const int k0 = w * 160 + s * 32;
            float4 qa = *(const float4*)(Qrow + k0);
            float4 qb = *(const float4*)(Qrow + k0 + 4);
            float qs[8] = {qa.x, qa.y, qa.z, qa.w, qb.x, qb.y, qb.z, qb.w};
            bf16x8 qh, ql, q2h;
#pragma unroll
            for (int j = 0; j < 8; ++j) {
                short h, l;
                split2(qs[j], h, l);
                qh[j] = h; ql[j] = l;
                q2h[j] = (short)bf16_rne(qs[j] * qs[j]);
            }
#pragma unroll
            for (int ct = 0; ct < 2; ++ct) {
                const int wi = ct * 16 + l15;
                const size_t bo = (size_t)wi * FEAT + k0 + l4 * 8;
                bf16x8 fvh = *(const bf16x8*)(Vhi + bo);
                bf16x8 fvl = *(const bf16x8*)(Vlo + bo);
                bf16x8 fmh = *(const bf16x8*)(Mhi + bo);
                bf16x8 fml = *(const bf16x8*)(Mlo + bo);
                bf16x8 fgh = *(const bf16x8*)(Ghi + bo);
                bf16x8 fgl = *(const bf16x8*)(Glo + bo);
                c[ct][0] = __builtin_amdgcn_mfma_f32_16x16x32_bf16(qh,   fvh, c[ct][0], 0, 0, 0);
                c[ct][1] = __builtin_amdgcn_mfma_f32_16x16x32_bf16(ql,   fvh, c[ct][1], 0, 0, 0);
                c[ct][2] = __builtin_amdgcn_mfma_f32_16x16x32_bf16(qh,   fvl, c[ct][2], 0, 0, 0);
                c[ct][3] = __builtin_amdgcn_mfma_f32_16x16x32_bf16(q2h,  fmh, c[ct][3], 0, 0, 0);
                c[ct][4] = __builtin_amdgcn_mfma_f32_16x16x32_bf16(q2h,  fml, c[ct][4], 0, 0, 0);
                c[ct][5] = __builtin_amdgcn_mfma_f32_16x16x32_bf16(ones, fgh, c[ct][5], 0, 0, 0);
                c[ct][6] = __builtin_amdgcn_mfma_f32_16x16x32_bf16(ones, fgl, c[ct][6], 0, 0, 0);
            }
        }

#pragma unroll
        for (int ct = 0; ct < 2; ++ct) {
            f32x4 acc = ((c[ct][0] + c[ct][1]) + (c[ct][2] + c[ct][3]))
                      + ((c[ct][4] + c[ct][5]) + c[ct][6]);
#pragma unroll
            for (int r = 0; r < 4; ++r)
                red[w][l4 * 4 + r][ct * 16 + l15] = acc[r];
        }
        __syncthreads();

#pragma unroll
        for (int e = tid; e < 512; e += 256) {
            const int qs_ = e >> 5, wl = e & 31;
            float v = red[0][qs_][wl] + red[1][qs_][wl] + red[2][qs_][wl] + red[3][qs_][wl];
            out[(q0 + qs_) * WAY + wl] = -sqrtf(fmaxf(v, 0.0f));
        }
    }
}

extern "C" void kernel_launch(void* const* d_in, const int* in_sizes, int n_in,
                              void* d_out, int out_size, void* d_ws, size_t ws_size,
                              hipStream_t stream) {
    const float* S  = (const float*)d_in[0];   // [32, 640]
    const float* Q  = (const float*)d_in[1];   // [4096, 640]
    const float* W1 = (const float*)d_in[2];   // [640, 1280]
    const float* b1 = (const float*)d_in[3];   // [640]
    const float* W2 = (const float*)d_in[4];   // [640, 640]
    const float* b2 = (const float*)d_in[5];   // [640]
    float* out = (float*)d_out;                // [4096, 32]

    char* wsb = (char*)d_ws;
    float* A    = (float*)wsb;                               // 32*640 f32
    float* B    = A + WAY * FEAT;                            // 32*640 f32
    float* part = B + WAY * FEAT;                            // 31*2*640 f32
    unsigned short* whi = (unsigned short*)(part + 31 * 2 * FEAT);  // 640*640 u16
    unsigned short* wlo = whi + FEAT * FEAT;                 // 640*640 u16
    unsigned short* Vhi = wlo + FEAT * FEAT;                 // 32*640 u16 each
    unsigned short* Vlo = Vhi + WAY * FEAT;
    unsigned short* Mhi = Vlo + WAY * FEAT;
    unsigned short* Mlo = Mhi + WAY * FEAT;
    unsigned short* Ghi = Mlo + WAY * FEAT;
    unsigned short* Glo = Ghi + WAY * FEAT;
    int* sync = (int*)(Glo + WAY * FEAT);                    // 2 ints
    (void)ws_size; (void)in_sizes; (void)n_in; (void)out_size;

    k_zero<<<dim3(1), dim3(64), 0, stream>>>(sync);
    k_all<<<dim3(NB), dim3(256), 0, stream>>>(S, Q, W1, b1, W2, b2,
                                              A, B, whi, wlo, part,
                                              Vhi, Vlo, Mhi, Mlo, Ghi, Glo,
                                              sync, out);
}

// Round 10
// 48.743 us; speedup vs baseline: 4.0574x; 4.0574x over previous
//
#include <hip/hip_runtime.h>
#include <math.h>

#define WAY   32
#define QUERY 128
#define FEAT  640
#define NPAIR 992
#define WQ    4096

typedef short bf16x8  __attribute__((ext_vector_type(8)));
typedef short short4v __attribute__((ext_vector_type(4)));
typedef float f32x4   __attribute__((ext_vector_type(4)));

static __device__ __forceinline__ float leaky(float v) {
    return v >= 0.0f ? v : 0.2f * v;
}
static __device__ __forceinline__ float dot4(float4 a, float4 b) {
    return a.x * b.x + a.y * b.y + a.z * b.z + a.w * b.w;
}
static __device__ __forceinline__ unsigned bf16_rne(float x) {
    unsigned u = __builtin_bit_cast(unsigned, x);
    return (u + 0x7FFFu + ((u >> 16) & 1u)) >> 16;
}
static __device__ __forceinline__ void split2(float x, short& hi, short& lo) {
    unsigned h = bf16_rne(x);
    float fh = __builtin_bit_cast(float, h << 16);
    hi = (short)h;
    lo = (short)bf16_rne(x - fh);
}

// ---------------------------------------------------------------------------
// K_PRE: blocks 0..319:  A'[i,o] = S[i].W1[o,0:640] + b1[o]
//                        B'[i,o] = S[i].W1[o,640:1280]
//        blocks 320..719: split W2 -> whi/wlo bf16
__global__ __launch_bounds__(256) void k_pre(const float* __restrict__ S,
                                             const float* __restrict__ W1,
                                             const float* __restrict__ b1,
                                             const float* __restrict__ W2,
                                             float* __restrict__ A,
                                             float* __restrict__ B,
                                             unsigned short* __restrict__ whi,
                                             unsigned short* __restrict__ wlo) {
    const int bx = blockIdx.x;
    const int tid = threadIdx.x;
    if (bx < 320) {
        __shared__ float4 shS[32][33];
        __shared__ float red1[128];
        const int half = bx / 160;
        const int o0   = (bx % 160) * 4;
        const int i  = tid & 31;
        const int ol = (tid >> 5) & 3;
        const int fh = tid >> 7;
        const float4* Wrow = (const float4*)(W1 + (o0 + ol) * (2 * FEAT) + half * FEAT);
        float acc = 0.0f;
        for (int f0 = 0; f0 < FEAT; f0 += 128) {
            __syncthreads();
#pragma unroll
            for (int s = 0; s < 4; ++s) {
                int flat = tid + 256 * s;
                int si = flat >> 5, sf = flat & 31;
                shS[si][sf] = *(const float4*)(S + si * FEAT + f0 + 4 * sf);
            }
            __syncthreads();
            const int kb = (f0 >> 2) + fh * 16;
#pragma unroll
            for (int k = 0; k < 16; ++k)
                acc += dot4(shS[i][fh * 16 + k], Wrow[kb + k]);
        }
        if (fh) red1[tid & 127] = acc;
        __syncthreads();
        if (!fh) {
            float tot = acc + red1[tid & 127];
            if (half == 0) A[i * FEAT + o0 + ol] = tot + b1[o0 + ol];
            else           B[i * FEAT + o0 + ol] = tot;
        }
    } else {
        int e = (bx - 320) * 1024 + tid * 4;
        float4 w = *(const float4*)(W2 + e);
        short h0, l0, h1, l1, h2, l2, h3, l3;
        split2(w.x, h0, l0); split2(w.y, h1, l1);
        split2(w.z, h2, l2); split2(w.w, h3, l3);
        *(short4v*)(whi + e) = (short4v){h0, h1, h2, h3};
        *(short4v*)(wlo + e) = (short4v){l0, l1, l2, l3};
    }
}

// ---------------------------------------------------------------------------
// K3 (BK=64, ONE barrier/step, colsum epilogue): h2 = leaky(h1@W2^T + b2) in
// MFMA accs; never stored — block column-sums its 32 p-rows (split at the wi
// boundary) into part[pt][2][640]. bf16x3 MFMA 16x16x32, 4 waves, tile
// 32p x 64o, 10 K-steps, dbuf LDS. Safety of single barrier: after barrier(t)
// every wave finished write(t) AND compute(t-1) (program order); write(t+1)
// targets the buffer last read in compute(t-1) — no race with compute(t).
__global__ __launch_bounds__(256) void k3_mfma(const float* __restrict__ Ap,
                                               const float* __restrict__ Bp,
                                               const unsigned short* __restrict__ whi,
                                               const unsigned short* __restrict__ wlo,
                                               const float* __restrict__ b2,
                                               float* __restrict__ part) {
    __shared__ __align__(16) short lsA[2][2][8][32][8];  // [buf][hi/lo][kc][prow][8]
    __shared__ __align__(16) short lsB[2][2][8][64][8];  // [buf][hi/lo][kc][orow][8]
    const int pt = blockIdx.x;
    const int p0 = pt * 32;
    const int o0 = blockIdx.y * 64;
    const int tid = threadIdx.x;
    const int w    = tid >> 6;
    const int lane = tid & 63;
    const int l15 = lane & 15, l4 = lane >> 4;

    // A-staging: 32 rows x 64 k = 512 float4, 2 per thread
    int ar[2], ac4[2], akc[2], aof[2];
    // B-staging: 64 rows x 8 kc per polarity = 512 bf16x8, 2 per thread
    int br[2], bk[2];
#pragma unroll
    for (int s = 0; s < 2; ++s) {
        int flat = tid + 256 * s;
        ar[s]  = flat >> 4;
        ac4[s] = (flat & 15) << 2;
        akc[s] = ac4[s] >> 3;
        aof[s] = ac4[s] & 7;
        br[s]  = flat >> 3;
        bk[s]  = flat & 7;
    }
    const float* Arow[2];
    const float* Brow[2];
#pragma unroll
    for (int s = 0; s < 2; ++s) {
        const int p = p0 + ar[s];
        const int ia = p / 31;
        const int jj = p % 31;
        const int ja = jj + (jj >= ia ? 1 : 0);
        Arow[s] = Ap + ia * FEAT;   // b1 folded in
        Brow[s] = Bp + ja * FEAT;
    }
    const unsigned short* Whr[2];
    const unsigned short* Wlr[2];
#pragma unroll
    for (int s = 0; s < 2; ++s) {
        Whr[s] = whi + (size_t)(o0 + br[s]) * FEAT;
        Wlr[s] = wlo + (size_t)(o0 + br[s]) * FEAT;
    }

    float4 ra[2], rb[2];
    bf16x8 rwh[2], rwl[2];
#pragma unroll
    for (int s = 0; s < 2; ++s) {
        ra[s]  = *(const float4*)(Arow[s] + ac4[s]);
        rb[s]  = *(const float4*)(Brow[s] + ac4[s]);
        rwh[s] = *(const bf16x8*)(Whr[s] + bk[s] * 8);
        rwl[s] = *(const bf16x8*)(Wlr[s] + bk[s] * 8);
    }

    f32x4 acc[2][2] = {};   // [rt][g]

    for (int t = 0; t < FEAT / 64; ++t) {
        const int buf = t & 1;
        // ---- write phase (regs of step t)
#pragma unroll
        for (int s = 0; s < 2; ++s) {
            float h[4];
            h[0] = leaky(ra[s].x + rb[s].x);
            h[1] = leaky(ra[s].y + rb[s].y);
            h[2] = leaky(ra[s].z + rb[s].z);
            h[3] = leaky(ra[s].w + rb[s].w);
            short hi[4], lo[4];
#pragma unroll
            for (int j = 0; j < 4; ++j) split2(h[j], hi[j], lo[j]);
            *(short4v*)&lsA[buf][0][akc[s]][ar[s]][aof[s]] = (short4v){hi[0], hi[1], hi[2], hi[3]};
            *(short4v*)&lsA[buf][1][akc[s]][ar[s]][aof[s]] = (short4v){lo[0], lo[1], lo[2], lo[3]};
            *(bf16x8*)&lsB[buf][0][bk[s]][br[s]][0] = rwh[s];
            *(bf16x8*)&lsB[buf][1][bk[s]][br[s]][0] = rwl[s];
        }
        __syncthreads();
        // ---- prefetch t+1 (overlaps compute below)
        if (t < FEAT / 64 - 1) {
            const int f0 = (t + 1) * 64;
#pragma unroll
            for (int s = 0; s < 2; ++s) {
                ra[s]  = *(const float4*)(Arow[s] + f0 + ac4[s]);
                rb[s]  = *(const float4*)(Brow[s] + f0 + ac4[s]);
                rwh[s] = *(const bf16x8*)(Whr[s] + f0 + bk[s] * 8);
                rwl[s] = *(const bf16x8*)(Wlr[s] + f0 + bk[s] * 8);
            }
        }
        // ---- compute: 12 mfma, 4 independent 3-chains
#pragma unroll
        for (int g = 0; g < 2; ++g) {
            const int kc = g * 4 + l4;
            bf16x8 bh = *(const bf16x8*)&lsB[buf][0][kc][w * 16 + l15][0];
            bf16x8 bl = *(const bf16x8*)&lsB[buf][1][kc][w * 16 + l15][0];
#pragma unroll
            for (int rt = 0; rt < 2; ++rt) {
                bf16x8 ah = *(const bf16x8*)&lsA[buf][0][kc][rt * 16 + l15][0];
                bf16x8 al = *(const bf16x8*)&lsA[buf][1][kc][rt * 16 + l15][0];
                acc[rt][g] = __builtin_amdgcn_mfma_f32_16x16x32_bf16(ah, bh, acc[rt][g], 0, 0, 0);
                acc[rt][g] = __builtin_amdgcn_mfma_f32_16x16x32_bf16(ah, bl, acc[rt][g], 0, 0, 0);
                acc[rt][g] = __builtin_amdgcn_mfma_f32_16x16x32_bf16(al, bh, acc[rt][g], 0, 0, 0);
            }
        }
    }

    // ---- colsum epilogue: rows < rsplit -> wi0 (h=0), else wi0+1 (h=1)
    const int oo = o0 + w * 16 + l15;
    const float b2v = b2[oo];
    const int wi0 = p0 / 31;
    const int rsplit = (wi0 + 1) * 31 - p0;
    float s0 = 0.0f, s1 = 0.0f;
#pragma unroll
    for (int r = 0; r < 4; ++r) {
        float v = leaky(acc[0][0][r] + acc[0][1][r] + b2v);     // row l4*4+r
        if (l4 * 4 + r < rsplit) s0 += v; else s1 += v;
        v = leaky(acc[1][0][r] + acc[1][1][r] + b2v);           // row 16+l4*4+r
        if (16 + l4 * 4 + r < rsplit) s0 += v; else s1 += v;
    }
    s0 += __shfl_xor(s0, 16, 64);
    s0 += __shfl_xor(s0, 32, 64);
    s1 += __shfl_xor(s1, 16, 64);
    s1 += __shfl_xor(s1, 32, 64);
    if (l4 == 0) {
        part[(pt * 2 + 0) * FEAT + oo] = s0;
        part[(pt * 2 + 1) * FEAT + oo] = s1;
    }
}

// ---------------------------------------------------------------------------
// K4: VMG+palpha from part. grid (32 wi x 10 chunks), 64 thr.
//   cs = colsum(wi,o); m = (cs/31)^4; V=-2mS, M=m (bf16 hi/lo);
//   palpha[wi*10+ch] = sum_chunk m*S^2 (wave shuffle reduce).
__global__ __launch_bounds__(64) void k4_vmg(const float* __restrict__ part,
                                             const float* __restrict__ S,
                                             unsigned short* __restrict__ Vhi,
                                             unsigned short* __restrict__ Vlo,
                                             unsigned short* __restrict__ Mhi,
                                             unsigned short* __restrict__ Mlo,
                                             float* __restrict__ palpha) {
    const int wi = blockIdx.x;
    const int ch = blockIdx.y;
    const int o  = ch * 64 + threadIdx.x;
    const int pa = (31 * wi) >> 5;
    const int pb = (31 * wi + 30) >> 5;
    const int ha = wi - (32 * pa) / 31;
    const int hb = wi - (32 * pb) / 31;
    float cs = part[(pa * 2 + ha) * FEAT + o];
    if (pa != pb) cs += part[(pb * 2 + hb) * FEAT + o];
    float c1 = cs * (1.0f / 31.0f);
    float c2 = c1 * c1;
    float m  = c2 * c2;
    float sv = S[wi * FEAT + o];
    short h, l;
    split2(-2.0f * m * sv, h, l);
    Vhi[wi * FEAT + o] = (unsigned short)h;  Vlo[wi * FEAT + o] = (unsigned short)l;
    split2(m, h, l);
    Mhi[wi * FEAT + o] = (unsigned short)h;  Mlo[wi * FEAT + o] = (unsigned short)l;

    float partv = m * sv * sv;
#pragma unroll
    for (int off = 32; off > 0; off >>= 1)
        partv += __shfl_down(partv, off, 64);
    if (threadIdx.x == 0) palpha[wi * 10 + ch] = partv;
}

// ---------------------------------------------------------------------------
// K5 (R5 exact): out[q,wi] = -sqrt(alpha[wi] + q.V + q^2.M)
// Grid 256(q-tile) x 2(wi-half) = 512 blocks; 4 waves K-split (160 f each).
// 5 independent mfma chains per wave; deterministic LDS combine.
__global__ __launch_bounds__(256) void k5_mfma(const float* __restrict__ Q,
                                               const unsigned short* __restrict__ Vhi,
                                               const unsigned short* __restrict__ Vlo,
                                               const unsigned short* __restrict__ Mhi,
                                               const unsigned short* __restrict__ Mlo,
                                               const float* __restrict__ palpha,
                                               float* __restrict__ out) {
    __shared__ float red[4][16][16];
    __shared__ float shAl[16];
    const int q0 = blockIdx.x * 16;
    const int by = blockIdx.y;          // wi-half
    const int tid = threadIdx.x;
    const int w    = tid >> 6;
    const int lane = tid & 63;
    const int l15 = lane & 15, l4 = lane >> 4;
    const float* Qrow = Q + (size_t)(q0 + l15) * FEAT + l4 * 8;
    const int wi = by * 16 + l15;
    const unsigned short* vh = Vhi + (size_t)wi * FEAT + l4 * 8;
    const unsigned short* vl = Vlo + (size_t)wi * FEAT + l4 * 8;
    const unsigned short* mh = Mhi + (size_t)wi * FEAT + l4 * 8;
    const unsigned short* ml = Mlo + (size_t)wi * FEAT + l4 * 8;

    f32x4 c0 = {}, c1 = {}, c2 = {}, c3 = {}, c4 = {};

#pragma unroll
    for (int s = 0; s < 5; ++s) {
        const int k0 = w * 160 + s * 32;
        float4 qa = *(const float4*)(Qrow + k0);
        float4 qb = *(const float4*)(Qrow + k0 + 4);
        float qs[8] = {qa.x, qa.y, qa.z, qa.w, qb.x, qb.y, qb.z, qb.w};
        bf16x8 qh, ql, q2h;
#pragma unroll
        for (int j = 0; j < 8; ++j) {
            short h, l;
            split2(qs[j], h, l);
            qh[j] = h; ql[j] = l;
            q2h[j] = (short)bf16_rne(qs[j] * qs[j]);
        }
        bf16x8 fvh = *(const bf16x8*)(vh + k0);
        bf16x8 fvl = *(const bf16x8*)(vl + k0);
        bf16x8 fmh = *(const bf16x8*)(mh + k0);
        bf16x8 fml = *(const bf16x8*)(ml + k0);
        c0 = __builtin_amdgcn_mfma_f32_16x16x32_bf16(qh,  fvh, c0, 0, 0, 0);
        c1 = __builtin_amdgcn_mfma_f32_16x16x32_bf16(ql,  fvh, c1, 0, 0, 0);
        c2 = __builtin_amdgcn_mfma_f32_16x16x32_bf16(qh,  fvl, c2, 0, 0, 0);
        c3 = __builtin_amdgcn_mfma_f32_16x16x32_bf16(q2h, fmh, c3, 0, 0, 0);
        c4 = __builtin_amdgcn_mfma_f32_16x16x32_bf16(q2h, fml, c4, 0, 0, 0);
    }

    f32x4 acc = c0 + c1 + c2 + c3 + c4;
#pragma unroll
    for (int r = 0; r < 4; ++r)
        red[w][l4 * 4 + r][l15] = acc[r];
    if (tid < 16) {
        float a = 0.0f;
#pragma unroll
        for (int c = 0; c < 10; ++c)
            a += palpha[(by * 16 + tid) * 10 + c];
        shAl[tid] = a;
    }
    __syncthreads();

    {
        const int qs_ = tid >> 4, wl = tid & 15;
        float v = red[0][qs_][wl] + red[1][qs_][wl] + red[2][qs_][wl] + red[3][qs_][wl];
        float d2 = shAl[wl] + v;
        out[(q0 + qs_) * WAY + by * 16 + wl] = -sqrtf(fmaxf(d2, 0.0f));
    }
}

extern "C" void kernel_launch(void* const* d_in, const int* in_sizes, int n_in,
                              void* d_out, int out_size, void* d_ws, size_t ws_size,
                              hipStream_t stream) {
    const float* S  = (const float*)d_in[0];   // [32, 640]
    const float* Q  = (const float*)d_in[1];   // [4096, 640]
    const float* W1 = (const float*)d_in[2];   // [640, 1280]
    const float* b1 = (const float*)d_in[3];   // [640]
    const float* W2 = (const float*)d_in[4];   // [640, 640]
    const float* b2 = (const float*)d_in[5];   // [640]
    float* out = (float*)d_out;                // [4096, 32]

    char* wsb = (char*)d_ws;
    float* A      = (float*)wsb;                             // 32*640 f32
    float* B      = A + WAY * FEAT;                          // 32*640 f32
    float* part   = B + WAY * FEAT;                          // 31*2*640 f32
    float* palpha = part + 31 * 2 * FEAT;                    // 320 f32
    unsigned short* whi = (unsigned short*)(palpha + 320);   // 640*640 u16
    unsigned short* wlo = whi + FEAT * FEAT;                 // 640*640 u16
    unsigned short* Vhi = wlo + FEAT * FEAT;                 // 32*640 u16 each
    unsigned short* Vlo = Vhi + WAY * FEAT;
    unsigned short* Mhi = Vlo + WAY * FEAT;
    unsigned short* Mlo = Mhi + WAY * FEAT;
    (void)ws_size; (void)in_sizes; (void)n_in; (void)out_size;

    k_pre<<<dim3(720), dim3(256), 0, stream>>>(S, W1, b1, W2, A, B, whi, wlo);
    k3_mfma<<<dim3(31, 10), dim3(256), 0, stream>>>(A, B, whi, wlo, b2, part);
    k4_vmg<<<dim3(WAY, 10), dim3(64), 0, stream>>>(part, S, Vhi, Vlo, Mhi, Mlo, palpha);
    k5_mfma<<<dim3(WQ / 16, 2), dim3(256), 0, stream>>>(Q, Vhi, Vlo, Mhi, Mlo, palpha, out);
}